// Round 4
// baseline (128.657 us; speedup 1.0000x reference)
//
#include <hip/hip_runtime.h>
#include <cstdint>
#include <cstddef>

#define NQ 900
#define NC 91
#define NFLAT (NQ * NC)        // 81900
#define NF4 (NFLAT / 4)        // 20475 (81900 % 4 == 0)
#define BS 8
#define PRE_TOPK 10000
#define TOPK 100
#define IOU_THR 0.7f
#define NT 1024
#define NWAVES (NT / 64)
#define HB 2048                // bins on p (~44 elems/bin near cutoff)
#define BCAP 2048              // crossing-bin / lazy-sort scratch capacity
#define SCAP 10240
#define PRESORT 1024           // pre-sort bins starting below this position
#define PRESORT_ENDCAP 8192    // stash bound: <=8 qualifying positions/thread

// prob in (0,1) => fp32 bits monotone. 49-bit distinct key:
//   K = (probbits << 17) | (131071 - idx)  == lax.top_k order (score desc, idx asc)
__device__ __forceinline__ unsigned int prob_bits(float x) {
    return __float_as_uint(1.0f / (1.0f + expf(-x)));
}
__device__ __forceinline__ unsigned long long make_key(unsigned int pb, int i) {
    return ((unsigned long long)pb << 17) | (unsigned long long)(131071 - i);
}
__device__ __forceinline__ int bucket_of(unsigned int pb) {
    float p = __uint_as_float(pb);
    int bk = (int)(p * (float)HB);
    bk = bk < 0 ? 0 : bk;
    return bk > (HB - 1) ? (HB - 1) : bk;
}
__device__ __forceinline__ uint4 sig4(const float* lg, int j) {
    const float4 v = ((const float4*)lg)[j];
    uint4 r;
    r.x = prob_bits(v.x); r.y = prob_bits(v.y);
    r.z = prob_bits(v.z); r.w = prob_bits(v.w);
    return r;
}

extern "C" __global__ __launch_bounds__(NT)
void NMSPostProcess_70463233458602_kernel(const float* __restrict__ logits,
                                          const float* __restrict__ pboxes,
                                          const float* __restrict__ tsizes,
                                          float* __restrict__ out) {
    __shared__ unsigned long long sKeys[SCAP];   // 80 KB: top-10000, bucket-major
    __shared__ unsigned long long sBinB[BCAP];   // 16 KB: crossing bin + lazy-sort scratch
    __shared__ int sHist[HB];                    // raw counts (preserved)
    __shared__ int sScan[HB];                    // exclusive-above per bin (bucket start)
    __shared__ int sCur[HB];                     // scatter cursors
    __shared__ float sKx1[TOPK], sKy1[TOPK], sKx2[TOPK], sKy2[TOPK], sKa[TOPK];
    __shared__ float sFirst[6];
    __shared__ float sRedF[NWAVES];
    __shared__ int sBinCnt, sB, sRem, sAbove, sKept, sSortedEnd;
    __shared__ float sBmax;

    const int b = blockIdx.x;
    const int tid = threadIdx.x;
    const int wid = tid >> 6, lane = tid & 63;
    const float* lg = logits + (size_t)b * NFLAT;
    const float* bx = pboxes + (size_t)b * NQ * 4;
    const float img_h = tsizes[b * 2 + 0], img_w = tsizes[b * 2 + 1];

    // ---- pass 1: sigmoid + 2048-bin histogram on p ----
    sHist[tid] = 0; sHist[tid + NT] = 0;
    if (tid == 0) { sBinCnt = 0; sSortedEnd = 0; }
    __syncthreads();
    for (int j = tid; j < NF4; j += NT) {
        const uint4 v = sig4(lg, j);
        atomicAdd(&sHist[bucket_of(v.x)], 1);
        atomicAdd(&sHist[bucket_of(v.y)], 1);
        atomicAdd(&sHist[bucket_of(v.z)], 1);
        atomicAdd(&sHist[bucket_of(v.w)], 1);
    }
    __syncthreads();

    // ---- suffix-inclusive scan over 2048 bins ----
    sScan[tid] = sHist[tid]; sScan[tid + NT] = sHist[tid + NT];
    __syncthreads();
    for (int off = 1; off < HB; off <<= 1) {
        const int t0 = (tid + off < HB) ? sScan[tid + off] : 0;
        const int t1 = (tid + NT + off < HB) ? sScan[tid + NT + off] : 0;
        __syncthreads();
        sScan[tid] += t0; sScan[tid + NT] += t1;
        __syncthreads();
    }
    {   // crossing bin B: above(B) < 10000 <= above(B)+cnt(B); leave sScan = exclusive-above
        const int si0 = sScan[tid], c0 = sHist[tid];
        const int si1 = sScan[tid + NT], c1 = sHist[tid + NT];
        if (si0 >= PRE_TOPK && si0 - c0 < PRE_TOPK) { sB = tid;      sAbove = si0 - c0; sRem = PRE_TOPK - (si0 - c0); }
        if (si1 >= PRE_TOPK && si1 - c1 < PRE_TOPK) { sB = tid + NT; sAbove = si1 - c1; sRem = PRE_TOPK - (si1 - c1); }
        sScan[tid] = si0 - c0;      sCur[tid] = si0 - c0;
        sScan[tid + NT] = si1 - c1; sCur[tid + NT] = si1 - c1;
    }
    __syncthreads();
    const int B = sB, above = sAbove, rem = sRem;

    // ---- pass 2: recompute sigmoid (L2-warm), bucket-major scatter (>B) + collect bin B ----
    for (int j = tid; j < NF4; j += NT) {
        const uint4 v = sig4(lg, j);
        const unsigned int pv[4] = { v.x, v.y, v.z, v.w };
        #pragma unroll
        for (int q = 0; q < 4; ++q) {
            const int bk = bucket_of(pv[q]);
            if (bk > B) {
                const int pos = atomicAdd(&sCur[bk], 1);
                sKeys[pos] = make_key(pv[q], 4 * j + q);
            } else if (bk == B) {
                const int pos = atomicAdd(&sBinCnt, 1);
                if (pos < BCAP) sBinB[pos] = make_key(pv[q], 4 * j + q);
            }
        }
    }
    __syncthreads();

    // ---- exact rank-select inside crossing bin -> sorted region [above, 10000) ----
    int cntB = sBinCnt; if (cntB > BCAP) cntB = BCAP;
    for (int jj = tid; jj < cntB; jj += NT) {
        const unsigned long long kj = sBinB[jj];
        int r = 0;
        for (int q = 0; q < cntB; ++q) r += (sBinB[q] > kj) ? 1 : 0;
        if (r < rem) sKeys[above + r] = kj;
    }
    __syncthreads();

    // ---- bmax over the exact top-10000 (membership only; order irrelevant) ----
    float lmax = -3.4e38f;
    for (int p = tid; p < PRE_TOPK; p += NT) {
        const int i = 131071 - (int)(sKeys[p] & 0x1FFFFULL);
        const int bi = i / NC;
        const float4 bb = ((const float4*)bx)[bi];
        const float x1 = (bb.x - 0.5f * bb.z) * img_w;
        const float y1 = (bb.y - 0.5f * bb.w) * img_h;
        const float x2 = (bb.x + 0.5f * bb.z) * img_w;
        const float y2 = (bb.y + 0.5f * bb.w) * img_h;
        lmax = fmaxf(lmax, fmaxf(fmaxf(x1, y1), fmaxf(x2, y2)));
    }
    for (int off = 32; off >= 1; off >>= 1)
        lmax = fmaxf(lmax, __shfl_xor(lmax, off, 64));
    if (lane == 0) sRedF[wid] = lmax;
    __syncthreads();
    if (tid == 0) {
        float mm = sRedF[0];
        for (int k = 1; k < NWAVES; ++k) mm = fmaxf(mm, sRedF[k]);
        sBmax = mm;
    }
    // ---- sorted-prefix extent: bins (>B) starting below PRESORT ----
    {
        const int bks[2] = { tid, tid + NT };
        #pragma unroll
        for (int q = 0; q < 2; ++q) {
            const int bk = bks[q];
            if (bk > B && sHist[bk] > 0 && sScan[bk] < PRESORT) {
                const int e = sScan[bk] + sHist[bk];
                if (e <= PRESORT_ENDCAP) atomicMax(&sSortedEnd, e);
            }
        }
    }
    __syncthreads();
    const float offc = sBmax + 1.0f;   // labels * (boxes.max() + 1)
    const int rawEnd = sSortedEnd;     // <= above; contiguous coverage [0, rawEnd)

    // ---- parallel pre-sort of positions [0, rawEnd) (in-bucket rank, all waves) ----
    {
        unsigned long long stash[8]; int spos[8]; int ns = 0;
        for (int p = tid; p < rawEnd; p += NT) {
            const unsigned long long k = sKeys[p];
            const int bk = bucket_of((unsigned int)(k >> 17));
            const int s0 = sScan[bk], len = sHist[bk];
            int r = 0;
            for (int q = 0; q < len; ++q) r += (sKeys[s0 + q] > k) ? 1 : 0;
            if (ns < 8) { stash[ns] = k; spos[ns] = s0 + r; ++ns; }
        }
        __syncthreads();
        for (int q = 0; q < ns; ++q) sKeys[spos[q]] = stash[q];
    }
    __syncthreads();

    // ---- sorted-scan NMS (wave 0; lazy bucket sort past the prefix) ----
    if (wid == 0) {
        int kept = 0;
        int sortedEnd = (rawEnd >= above) ? PRE_TOPK : rawEnd;
        int curBin = HB - 1;
        for (int base = 0; base < PRE_TOPK && kept < TOPK; base += 64) {
            const int need = (base + 64 < PRE_TOPK) ? base + 64 : PRE_TOPK;
            while (sortedEnd < need) {                    // lazy extension (rare)
                if (sortedEnd >= above) { sortedEnd = PRE_TOPK; break; }
                while (curBin > B && !(sScan[curBin] == sortedEnd && sHist[curBin] > 0)) --curBin;
                const int len0 = sHist[curBin];
                const int len = len0 > BCAP ? BCAP : len0;
                for (int q = lane; q < len; q += 64) sBinB[q] = sKeys[sortedEnd + q];
                for (int c0 = 0; c0 < len; c0 += 64) {
                    const int ii = c0 + lane;
                    const unsigned long long kk = (ii < len) ? sBinB[ii] : 0ULL;
                    int r = 0;
                    for (int q = 0; q < len; ++q) r += (sBinB[q] > kk) ? 1 : 0;
                    if (ii < len) sKeys[sortedEnd + r] = kk;
                }
                sortedEnd += len0;
                --curBin;
            }
            const int c = base + lane;
            const bool valid = c < PRE_TOPK;
            const unsigned long long k = valid ? sKeys[c] : 0ULL;
            const int i = valid ? (131071 - (int)(k & 0x1FFFFULL)) : 0;
            const int bi = i / NC, l = i - bi * NC;
            const float4 bb = ((const float4*)bx)[bi];
            const float bx1 = (bb.x - 0.5f * bb.z) * img_w;
            const float by1 = (bb.y - 0.5f * bb.w) * img_h;
            const float bx2 = (bb.x + 0.5f * bb.z) * img_w;
            const float by2 = (bb.y + 0.5f * bb.w) * img_h;
            const float o = (float)l * offc;
            const float ox1 = bx1 + o, oy1 = by1 + o, ox2 = bx2 + o, oy2 = by2 + o;
            const float ar = (ox2 - ox1) * (oy2 - oy1);
            bool alive = valid;
            for (int jj = 0; jj < kept; ++jj) {           // vs all earlier keeps
                float iw = fminf(sKx2[jj], ox2) - fmaxf(sKx1[jj], ox1);
                float ih = fminf(sKy2[jj], oy2) - fmaxf(sKy1[jj], oy1);
                iw = fmaxf(iw, 0.f); ih = fmaxf(ih, 0.f);
                const float inter = iw * ih;
                if (inter > IOU_THR * (sKa[jj] + ar - inter)) alive = false;
            }
            unsigned long long mask = __ballot(alive);
            while (mask != 0ULL && kept < TOPK) {
                const int s = __ffsll((unsigned long long)mask) - 1;  // highest alive
                const float px1 = __shfl(ox1, s, 64);
                const float py1 = __shfl(oy1, s, 64);
                const float px2 = __shfl(ox2, s, 64);
                const float py2 = __shfl(oy2, s, 64);
                const float pa  = __shfl(ar,  s, 64);
                if (lane == s) {
                    sKx1[kept] = ox1; sKy1[kept] = oy1; sKx2[kept] = ox2; sKy2[kept] = oy2; sKa[kept] = ar;
                    const int oi = b * TOPK + kept;
                    const float sc = __uint_as_float((unsigned int)(k >> 17));
                    out[oi] = sc;
                    out[BS * TOPK + oi] = (float)l;
                    out[2 * BS * TOPK + oi * 4 + 0] = bx1;
                    out[2 * BS * TOPK + oi * 4 + 1] = by1;
                    out[2 * BS * TOPK + oi * 4 + 2] = bx2;
                    out[2 * BS * TOPK + oi * 4 + 3] = by2;
                    if (kept == 0) { sFirst[0] = sc; sFirst[1] = (float)l;
                                     sFirst[2] = bx1; sFirst[3] = by1;
                                     sFirst[4] = bx2; sFirst[5] = by2; }
                }
                ++kept;
                if (alive) {   // suppress vs the new keep (self IoU=1 -> dies)
                    float iw = fminf(px2, ox2) - fmaxf(px1, ox1);
                    float ih = fminf(py2, oy2) - fmaxf(py1, oy1);
                    iw = fmaxf(iw, 0.f); ih = fmaxf(ih, 0.f);
                    const float inter = iw * ih;
                    if (inter > IOU_THR * (pa + ar - inter)) alive = false;
                }
                mask = __ballot(alive);
            }
        }
        if (lane == 0) sKept = kept;
    }
    __syncthreads();
    // exhaustion: ref's argmax over all -inf -> index 0 -> replicate row 0
    for (int t = sKept + tid; t < TOPK; t += NT) {
        const int oi = b * TOPK + t;
        out[oi] = sFirst[0];
        out[BS * TOPK + oi] = sFirst[1];
        out[2 * BS * TOPK + oi * 4 + 0] = sFirst[2];
        out[2 * BS * TOPK + oi * 4 + 1] = sFirst[3];
        out[2 * BS * TOPK + oi * 4 + 2] = sFirst[4];
        out[2 * BS * TOPK + oi * 4 + 3] = sFirst[5];
    }
}

extern "C" void kernel_launch(void* const* d_in, const int* in_sizes, int n_in,
                              void* d_out, int out_size, void* d_ws, size_t ws_size,
                              hipStream_t stream) {
    const float* logits = (const float*)d_in[0];   // (8, 900, 91) fp32
    const float* pboxes = (const float*)d_in[1];   // (8, 900, 4) fp32
    const float* ts     = (const float*)d_in[2];   // (8, 2) fp32
    hipLaunchKernelGGL(NMSPostProcess_70463233458602_kernel,
                       dim3(BS), dim3(NT), 0, stream,
                       logits, pboxes, ts, (float*)d_out);
}

// Round 5
// 109.507 us; speedup vs baseline: 1.1749x; 1.1749x over previous
//
#include <hip/hip_runtime.h>
#include <cstdint>
#include <cstddef>

#define NQ 900
#define NC 91
#define NFLAT (NQ * NC)        // 81900
#define NF4 (NFLAT / 4)        // 20475 (81900 % 4 == 0)
#define BS 8
#define PRE_TOPK 10000
#define TOPK 100
#define IOU_THR 0.7f
#define NT 1024
#define NWAVES (NT / 64)
#define HB 2048                // bins on z over [-4,4) (~64 elems/bin near cutoff)
#define BCAP 2048              // crossing-bin / lazy-sort scratch capacity
#define SCAP 10240
#define PRESORT 1024           // pre-sort bins starting below this position
#define PRESORT_ENDCAP 8192    // stash bound: <=8 qualifying positions/thread

// sigmoid is monotone => order on raw logit z == order on prob.
// Monotone unsigned map of fp32 bits (works for all finite z):
__device__ __forceinline__ unsigned int mono_u(float z) {
    unsigned int b = __float_as_uint(z);
    return b ^ ((unsigned int)((int)b >> 31) | 0x80000000u);
}
__device__ __forceinline__ float inv_mono(unsigned int u) {
    unsigned int b = (u & 0x80000000u) ? (u ^ 0x80000000u) : ~u;
    return __uint_as_float(b);
}
// 49-bit distinct key: (u << 17) | (131071 - idx)  == lax.top_k order (score desc, idx asc)
__device__ __forceinline__ unsigned long long make_key(unsigned int u, int i) {
    return ((unsigned long long)u << 17) | (unsigned long long)(131071 - i);
}
// linear-in-z bin, monotone (clamped at the ends)
__device__ __forceinline__ int bin_of(float z) {
    float t = (z + 4.0f) * 256.0f;          // HB/8 = 256
    t = fmaxf(t, 0.0f); t = fminf(t, 2047.0f);
    return (int)t;
}

extern "C" __global__ __launch_bounds__(NT)
void NMSPostProcess_70463233458602_kernel(const float* __restrict__ logits,
                                          const float* __restrict__ pboxes,
                                          const float* __restrict__ tsizes,
                                          float* __restrict__ out) {
    __shared__ unsigned long long sKeys[SCAP];   // 80 KB: top-10000, bucket-major
    __shared__ unsigned long long sBinB[BCAP];   // 16 KB: crossing bin + lazy-sort scratch
    __shared__ int sHist[HB];                    // raw counts (preserved)
    __shared__ int sScan[HB];                    // exclusive-above per bin (bucket start)
    __shared__ int sCur[HB];                     // scatter cursors
    __shared__ float sKx1[TOPK], sKy1[TOPK], sKx2[TOPK], sKy2[TOPK], sKa[TOPK];
    __shared__ float sFirst[6];
    __shared__ float sRedF[NWAVES];
    __shared__ int sWTot[NWAVES], sWSuf[NWAVES];
    __shared__ int sBinCnt, sB, sRem, sAbove, sKept, sSortedEnd, sCnt2, sPos;
    __shared__ float sBmax;

    const int b = blockIdx.x;
    const int tid = threadIdx.x;
    const int wid = tid >> 6, lane = tid & 63;
    const float* lg = logits + (size_t)b * NFLAT;
    const float* bx = pboxes + (size_t)b * NQ * 4;
    const float img_h = tsizes[b * 2 + 0], img_w = tsizes[b * 2 + 1];

    // ---- pass 1: 2048-bin histogram on raw logit z (no sigmoid!) ----
    sHist[tid] = 0; sHist[tid + NT] = 0;
    if (tid == 0) { sBinCnt = 0; sSortedEnd = 0; sPos = 0; }
    __syncthreads();
    #pragma unroll 2
    for (int j = tid; j < NF4; j += NT) {
        const float4 v = ((const float4*)lg)[j];
        atomicAdd(&sHist[bin_of(v.x)], 1);
        atomicAdd(&sHist[bin_of(v.y)], 1);
        atomicAdd(&sHist[bin_of(v.z)], 1);
        atomicAdd(&sHist[bin_of(v.w)], 1);
    }
    __syncthreads();

    // ---- shfl-based hierarchical suffix scan (4 barriers, not 22) ----
    // thread owns bin pair (2*tid, 2*tid+1); pair index within wave = lane
    {
        const int b0 = 2 * tid, b1 = 2 * tid + 1;
        const int h0 = sHist[b0], h1 = sHist[b1];
        const int s = h0 + h1;
        int v = s;                              // inclusive suffix over lanes in wave
        #pragma unroll
        for (int off = 1; off < 64; off <<= 1) {
            const int o = __shfl(v, lane + off, 64);
            if (lane + off < 64) v += o;
        }
        if (lane == 0) sWTot[wid] = v;          // wave total
        __syncthreads();
        if (wid == 0) {
            int t = (lane < NWAVES) ? sWTot[lane] : 0;
            #pragma unroll
            for (int off = 1; off < NWAVES; off <<= 1) {
                const int o = __shfl(t, lane + off, 64);
                if (lane + off < NWAVES) t += o;
            }
            if (lane < NWAVES) sWSuf[lane] = t; // inclusive suffix over waves
        }
        __syncthreads();
        const int afterWave = sWSuf[wid] - sWTot[wid];
        const int afterPairs = (v - s) + afterWave;   // elems in bins > b1
        const int si1 = h1 + afterPairs;              // suffix-inclusive at b1
        const int si0 = h0 + si1;                     // at b0
        const int ea0 = si1, ea1 = afterPairs;        // exclusive-above
        sScan[b0] = ea0; sCur[b0] = ea0;
        sScan[b1] = ea1; sCur[b1] = ea1;
        if (si0 >= PRE_TOPK && ea0 < PRE_TOPK) { sB = b0; sAbove = ea0; sRem = PRE_TOPK - ea0; }
        if (si1 >= PRE_TOPK && ea1 < PRE_TOPK) { sB = b1; sAbove = ea1; sRem = PRE_TOPK - ea1; }
    }
    __syncthreads();
    const int B = sB, above = sAbove, rem = sRem;

    // ---- pass 2: bucket-major scatter (>B) + collect crossing bin (no sigmoid) ----
    #pragma unroll 2
    for (int j = tid; j < NF4; j += NT) {
        const float4 v = ((const float4*)lg)[j];
        const float zv[4] = { v.x, v.y, v.z, v.w };
        #pragma unroll
        for (int q = 0; q < 4; ++q) {
            const int bk = bin_of(zv[q]);
            if (bk > B) {
                const int pos = atomicAdd(&sCur[bk], 1);
                sKeys[pos] = make_key(mono_u(zv[q]), 4 * j + q);
            } else if (bk == B) {
                const int pos = atomicAdd(&sBinCnt, 1);
                if (pos < BCAP) sBinB[pos] = make_key(mono_u(zv[q]), 4 * j + q);
            }
        }
    }
    __syncthreads();

    const int cntBraw = sBinCnt;
    if (cntBraw <= BCAP) {
        // ---- normal: exact rank-select in crossing bin -> sorted [above, 10000) ----
        for (int jj = tid; jj < cntBraw; jj += NT) {
            const unsigned long long kj = sBinB[jj];
            int r = 0;
            for (int q = 0; q < cntBraw; ++q) r += (sBinB[q] > kj) ? 1 : 0;
            if (r < rem) sKeys[above + r] = kj;
        }
        __syncthreads();
    } else {
        // ---- fallback (never taken on sane input): binary-search exact threshold ----
        unsigned long long lo = 0, hi = (1ULL << 49) - 1;
        while (lo < hi) {
            const unsigned long long mid = lo + ((hi - lo + 1) >> 1);
            int c = 0;
            for (int j = tid; j < NF4; j += NT) {
                const float4 v = ((const float4*)lg)[j];
                const float zv[4] = { v.x, v.y, v.z, v.w };
                #pragma unroll
                for (int q = 0; q < 4; ++q)
                    c += (make_key(mono_u(zv[q]), 4 * j + q) >= mid) ? 1 : 0;
            }
            for (int off = 32; off >= 1; off >>= 1) c += __shfl_xor(c, off, 64);
            if (lane == 0) sWTot[wid] = c;
            __syncthreads();
            if (tid == 0) {
                int a = 0;
                for (int w = 0; w < NWAVES; ++w) a += sWTot[w];
                sCnt2 = a;
            }
            __syncthreads();
            if (sCnt2 >= PRE_TOPK) lo = mid; else hi = mid - 1;
            __syncthreads();
        }
        const unsigned long long T = lo;   // exact 10000th-largest key
        for (int j = tid; j < NF4; j += NT) {
            const float4 v = ((const float4*)lg)[j];
            const float zv[4] = { v.x, v.y, v.z, v.w };
            #pragma unroll
            for (int q = 0; q < 4; ++q) {
                if (bin_of(zv[q]) == B) {
                    const unsigned long long k = make_key(mono_u(zv[q]), 4 * j + q);
                    if (k >= T) { const int pos = atomicAdd(&sPos, 1); sKeys[above + pos] = k; }
                }
            }
        }
        __syncthreads();
        // rank-sort [above, 10000) (stash two-phase; rem/NT <= 10)
        unsigned long long stash[10]; int spp[10]; int ns = 0;
        for (int p = above + tid; p < PRE_TOPK; p += NT) {
            const unsigned long long k = sKeys[p];
            int r = 0;
            for (int q = above; q < PRE_TOPK; ++q) r += (sKeys[q] > k) ? 1 : 0;
            if (ns < 10) { stash[ns] = k; spp[ns] = above + r; ++ns; }
        }
        __syncthreads();
        for (int q = 0; q < ns; ++q) sKeys[spp[q]] = stash[q];
        __syncthreads();
    }

    // ---- bmax over the exact top-10000 (membership only) ----
    float lmax = -3.4e38f;
    for (int p = tid; p < PRE_TOPK; p += NT) {
        const int i = 131071 - (int)(sKeys[p] & 0x1FFFFULL);
        const int bi = i / NC;
        const float4 bb = ((const float4*)bx)[bi];
        const float x1 = (bb.x - 0.5f * bb.z) * img_w;
        const float y1 = (bb.y - 0.5f * bb.w) * img_h;
        const float x2 = (bb.x + 0.5f * bb.z) * img_w;
        const float y2 = (bb.y + 0.5f * bb.w) * img_h;
        lmax = fmaxf(lmax, fmaxf(fmaxf(x1, y1), fmaxf(x2, y2)));
    }
    for (int off = 32; off >= 1; off >>= 1)
        lmax = fmaxf(lmax, __shfl_xor(lmax, off, 64));
    if (lane == 0) sRedF[wid] = lmax;
    __syncthreads();
    if (tid == 0) {
        float mm = sRedF[0];
        for (int k = 1; k < NWAVES; ++k) mm = fmaxf(mm, sRedF[k]);
        sBmax = mm;
    }
    // ---- sorted-prefix extent: bins (>B) starting below PRESORT ----
    {
        const int bks[2] = { 2 * tid, 2 * tid + 1 };
        #pragma unroll
        for (int q = 0; q < 2; ++q) {
            const int bk = bks[q];
            if (bk > B && sHist[bk] > 0 && sScan[bk] < PRESORT) {
                const int e = sScan[bk] + sHist[bk];
                if (e <= PRESORT_ENDCAP) atomicMax(&sSortedEnd, e);
            }
        }
    }
    __syncthreads();
    const float offc = sBmax + 1.0f;   // labels * (boxes.max() + 1)
    const int rawEnd = sSortedEnd;     // <= above; contiguous coverage [0, rawEnd)

    // ---- parallel pre-sort of positions [0, rawEnd) (in-bucket rank) ----
    {
        unsigned long long stash[8]; int spos[8]; int ns = 0;
        for (int p = tid; p < rawEnd; p += NT) {
            const unsigned long long k = sKeys[p];
            const int bk = bin_of(inv_mono((unsigned int)(k >> 17)));
            const int s0 = sScan[bk], len = sHist[bk];
            int r = 0;
            for (int q = 0; q < len; ++q) r += (sKeys[s0 + q] > k) ? 1 : 0;
            if (ns < 8) { stash[ns] = k; spos[ns] = s0 + r; ++ns; }
        }
        __syncthreads();
        for (int q = 0; q < ns; ++q) sKeys[spos[q]] = stash[q];
    }
    __syncthreads();

    // ---- sorted-scan NMS (wave 0; lazy bucket sort past the prefix) ----
    if (wid == 0) {
        int kept = 0;
        int sortedEnd = (rawEnd >= above) ? PRE_TOPK : rawEnd;
        int curBin = HB - 1;
        for (int base = 0; base < PRE_TOPK && kept < TOPK; base += 64) {
            const int need = (base + 64 < PRE_TOPK) ? base + 64 : PRE_TOPK;
            while (sortedEnd < need) {                    // lazy extension (rare)
                if (sortedEnd >= above) { sortedEnd = PRE_TOPK; break; }
                while (curBin > B && !(sScan[curBin] == sortedEnd && sHist[curBin] > 0)) --curBin;
                const int len0 = sHist[curBin];
                const int len = len0 > BCAP ? BCAP : len0;
                for (int q = lane; q < len; q += 64) sBinB[q] = sKeys[sortedEnd + q];
                for (int c0 = 0; c0 < len; c0 += 64) {
                    const int ii = c0 + lane;
                    const unsigned long long kk = (ii < len) ? sBinB[ii] : 0ULL;
                    int r = 0;
                    for (int q = 0; q < len; ++q) r += (sBinB[q] > kk) ? 1 : 0;
                    if (ii < len) sKeys[sortedEnd + r] = kk;
                }
                sortedEnd += len0;
                --curBin;
            }
            const int c = base + lane;
            const bool valid = c < PRE_TOPK;
            const unsigned long long k = valid ? sKeys[c] : 0ULL;
            const int i = valid ? (131071 - (int)(k & 0x1FFFFULL)) : 0;
            const int bi = i / NC, l = i - bi * NC;
            const float4 bb = ((const float4*)bx)[bi];
            const float bx1 = (bb.x - 0.5f * bb.z) * img_w;
            const float by1 = (bb.y - 0.5f * bb.w) * img_h;
            const float bx2 = (bb.x + 0.5f * bb.z) * img_w;
            const float by2 = (bb.y + 0.5f * bb.w) * img_h;
            const float o = (float)l * offc;
            const float ox1 = bx1 + o, oy1 = by1 + o, ox2 = bx2 + o, oy2 = by2 + o;
            const float ar = (ox2 - ox1) * (oy2 - oy1);
            bool alive = valid;
            for (int jj = 0; jj < kept; ++jj) {           // vs all earlier keeps
                float iw = fminf(sKx2[jj], ox2) - fmaxf(sKx1[jj], ox1);
                float ih = fminf(sKy2[jj], oy2) - fmaxf(sKy1[jj], oy1);
                iw = fmaxf(iw, 0.f); ih = fmaxf(ih, 0.f);
                const float inter = iw * ih;
                if (inter > IOU_THR * (sKa[jj] + ar - inter)) alive = false;
            }
            unsigned long long mask = __ballot(alive);
            while (mask != 0ULL && kept < TOPK) {
                const int s = __ffsll((unsigned long long)mask) - 1;  // highest alive
                const float px1 = __shfl(ox1, s, 64);
                const float py1 = __shfl(oy1, s, 64);
                const float px2 = __shfl(ox2, s, 64);
                const float py2 = __shfl(oy2, s, 64);
                const float pa  = __shfl(ar,  s, 64);
                if (lane == s) {
                    sKx1[kept] = ox1; sKy1[kept] = oy1; sKx2[kept] = ox2; sKy2[kept] = oy2; sKa[kept] = ar;
                    const int oi = b * TOPK + kept;
                    const float z = inv_mono((unsigned int)(k >> 17));
                    const float sc = 1.0f / (1.0f + expf(-z));   // sigmoid only for outputs
                    out[oi] = sc;
                    out[BS * TOPK + oi] = (float)l;
                    out[2 * BS * TOPK + oi * 4 + 0] = bx1;
                    out[2 * BS * TOPK + oi * 4 + 1] = by1;
                    out[2 * BS * TOPK + oi * 4 + 2] = bx2;
                    out[2 * BS * TOPK + oi * 4 + 3] = by2;
                    if (kept == 0) { sFirst[0] = sc; sFirst[1] = (float)l;
                                     sFirst[2] = bx1; sFirst[3] = by1;
                                     sFirst[4] = bx2; sFirst[5] = by2; }
                }
                ++kept;
                if (alive) {   // suppress vs the new keep (self IoU=1 -> dies)
                    float iw = fminf(px2, ox2) - fmaxf(px1, ox1);
                    float ih = fminf(py2, oy2) - fmaxf(py1, oy1);
                    iw = fmaxf(iw, 0.f); ih = fmaxf(ih, 0.f);
                    const float inter = iw * ih;
                    if (inter > IOU_THR * (pa + ar - inter)) alive = false;
                }
                mask = __ballot(alive);
            }
        }
        if (lane == 0) sKept = kept;
    }
    __syncthreads();
    // exhaustion: ref's argmax over all -inf -> index 0 -> replicate row 0
    for (int t = sKept + tid; t < TOPK; t += NT) {
        const int oi = b * TOPK + t;
        out[oi] = sFirst[0];
        out[BS * TOPK + oi] = sFirst[1];
        out[2 * BS * TOPK + oi * 4 + 0] = sFirst[2];
        out[2 * BS * TOPK + oi * 4 + 1] = sFirst[3];
        out[2 * BS * TOPK + oi * 4 + 2] = sFirst[4];
        out[2 * BS * TOPK + oi * 4 + 3] = sFirst[5];
    }
}

extern "C" void kernel_launch(void* const* d_in, const int* in_sizes, int n_in,
                              void* d_out, int out_size, void* d_ws, size_t ws_size,
                              hipStream_t stream) {
    const float* logits = (const float*)d_in[0];   // (8, 900, 91) fp32
    const float* pboxes = (const float*)d_in[1];   // (8, 900, 4) fp32
    const float* ts     = (const float*)d_in[2];   // (8, 2) fp32
    hipLaunchKernelGGL(NMSPostProcess_70463233458602_kernel,
                       dim3(BS), dim3(NT), 0, stream,
                       logits, pboxes, ts, (float*)d_out);
}